// Round 7
// baseline (17.604 us; speedup 1.0000x reference)
//
#include <hip/hip_runtime.h>

// B-spline activation (KAN-style), fp32.
// x: (8192, 1024) f32, coeff: (1024, 10) f32, out: (8192, 1024) f32.
// Structure (round 5): per-(feature, interval) power-basis float4 in LDS;
// tap fetch = ONE ds_read_b128 (j-independent banks); inner = 3 Horner FMAs.
// Round-6: (1) PROWS=64 -> 13KB LDS -> 12 blocks/CU capacity, no tail;
// (2) x-loads issued BEFORE staging (hide under coeff fetch);
// (3) staging 4-way parallel across all 256 threads (wave-uniform parts).

constexpr int NB = 10;           // N_BASES
constexpr int NJ = 13;           // intervals
constexpr int PROWS = 64;        // features per panel (16 panels)
constexpr int THREADS = 256;
constexpr int GRID = 2048;
constexpr int ITERS = 4;

__global__ __launch_bounds__(THREADS) void bspline_act_kernel(
    const float* __restrict__ x,
    const float* __restrict__ coeff,
    float* __restrict__ out)
{
    // lds4[j*64 + s]; slot s holds logical row r(s)=((s&15)<<2)|(s>>4), so the
    // reader of feature-group fg, element e hits slot e*16+fg (consecutive 16B
    // chunks across lanes; plane stride 1024B -> bank index j-independent).
    __shared__ float4 lds4[NJ * PROWS];          // 13 KB -> 12 blocks/CU
    const int t = threadIdx.x;
    const int b = blockIdx.x;
    const int panel = b & 15;                    // 64-feature panel
    const int rg = b >> 4;                       // 0..127
    const int fg = t & 15;                       // feature group (4 features)
    const int wr = t >> 4;                       // 0..15: row within stripe

    // --- x loads first: 4 independent float4 loads in flight before staging.
    float4 xv[ITERS];
    int E4[ITERS];
    #pragma unroll
    for (int k = 0; k < ITERS; ++k) {
        const int row = (rg + k * 128) * 16 + wr;        // batch row
        E4[k] = row * 256 + panel * 16 + fg;             // float4 index
        xv[k] = reinterpret_cast<const float4*>(x)[E4[k]];
    }

    // --- staging: thread (sr, sp) builds intervals 4sp..4sp+3 of row sr.
    {
        const int sr = t & 63;                   // staging row 0..63
        const int sp = t >> 6;                   // part 0..3 (uniform per wave)
        const float* src = coeff + (panel * PROWS + sr) * NB;
        float w[16];
        w[0] = w[1] = w[2] = 0.0f;
        w[13] = w[14] = w[15] = 0.0f;
        #pragma unroll
        for (int c = 0; c < 5; ++c) {
            const float2 pq = reinterpret_cast<const float2*>(src)[c];
            w[3 + 2 * c] = pq.x;
            w[4 + 2 * c] = pq.y;
        }
        const int slot = ((sr & 3) << 4) | (sr >> 2);    // inverse row swizzle
        #pragma unroll
        for (int jj = 0; jj < 4; ++jj) {
            const int j = sp * 4 + jj;
            if (j < NJ) {                        // wave-uniform (sp uniform)
                const float d0 = w[j], d1 = w[j + 1], d2 = w[j + 2], d3 = w[j + 3];
                float4 a;
                a.x = fmaf(4.0f, d1, d0 + d2) * (1.0f / 6.0f);      // a0
                a.y = (d2 - d0) * 0.5f;                             // a1
                a.z = (d0 + d2) * 0.5f - d1;                        // a2
                a.w = (d3 - d0) * (1.0f / 6.0f) + (d1 - d2) * 0.5f; // a3
                lds4[j * PROWS + slot] = a;      // bijective slots: conflict-free
            }
        }
    }
    __syncthreads();

    const float4* lbase = lds4 + fg;    // + e*16 + j*PROWS

    #pragma unroll
    for (int k = 0; k < ITERS; ++k) {
        const float xs[4] = {xv[k].x, xv[k].y, xv[k].z, xv[k].w};
        float res[4];
        #pragma unroll
        for (int e = 0; e < 4; ++e) {
            const float xc = fminf(fmaxf(xs[e], -1.0f), 1.0f);
            const float u = fmaf(xc, 6.5f, 6.5f);        // knot units [0,13]
            const float jf = fminf(truncf(u), 12.0f);
            const float tt = u - jf;                     // [0,1]
            const int j = (int)jf;

            const float4 a = lbase[e * 16 + j * PROWS];  // 1x ds_read_b128
            float r = fmaf(a.w, tt, a.z);
            r = fmaf(r, tt, a.y);
            r = fmaf(r, tt, a.x);
            // x==+1 (j=12, tt=1) and x==-1 (j=0, tt=0): zero pads give ~0
            // (<= ~1e-7), matching the reference's empty-indicator edges.
            res[e] = r;
        }
        const float4 ov = {res[0], res[1], res[2], res[3]};
        reinterpret_cast<float4*>(out)[E4[k]] = ov;
    }
}

extern "C" void kernel_launch(void* const* d_in, const int* in_sizes, int n_in,
                              void* d_out, int out_size, void* d_ws, size_t ws_size,
                              hipStream_t stream) {
    const float* x = (const float*)d_in[0];
    const float* coeff = (const float*)d_in[1];
    float* out = (float*)d_out;
    hipLaunchKernelGGL(bspline_act_kernel, dim3(GRID), dim3(THREADS), 0, stream,
                       x, coeff, out);
}

// Round 9
// 14.442 us; speedup vs baseline: 1.2190x; 1.2190x over previous
//
#include <hip/hip_runtime.h>

// B-spline activation (KAN-style), fp32.
// x: (8192, 1024) f32, coeff: (1024, 10) f32, out: (8192, 1024) f32.
// Structure = round-5 (best, 15.9us): per-(feature, interval) power-basis
// float4 in LDS; tap fetch = ONE ds_read_b128 (bank pattern j-independent);
// inner = 3 Horner FMAs. Staging by threads 0..127, x loads AFTER barrier
// (round-6 lesson: x-first delays coeff arrival in the in-order vmcnt queue).
// Round-8 lever: NON-TEMPORAL out stores (via native clang vector type —
// __builtin_nontemporal_store rejects HIP_vector_type) -> out never
// allocates in L2/L3, so x (32MB) stays L3-resident across replays
// (r1/r2 FETCH=16.5MB showed partial residency; out stream was evicting it).

typedef float f32x4 __attribute__((ext_vector_type(4)));

constexpr int NB = 10;           // N_BASES
constexpr int THREADS = 256;
constexpr int GRID = 2048;
constexpr int ITERS = 4;
constexpr int PROWS = 128;       // features per panel (8 panels)
constexpr int NJ = 13;           // intervals

__global__ __launch_bounds__(THREADS) void bspline_act_kernel(
    const float* __restrict__ x,
    const float* __restrict__ coeff,
    float* __restrict__ out)
{
    // lds4[j * PROWS + s]; slot s holds logical row r(s) = ((s&31)<<2)|(s>>5),
    // so the reader of feature-group fg, element e hits slot e*32+fg.
    __shared__ float4 lds4[NJ * PROWS];          // 26 KB -> 6 blocks/CU
    const int t = threadIdx.x;
    const int b = blockIdx.x;
    const int panel = b & 7;                     // 128-feature panel
    const int rg = b >> 3;                       // 0..255
    const int fg = t & 31;                       // feature group (4 features)
    const int wr = t >> 5;                       // 0..7: batch row within stripe

    // Staging: threads 0..127 each build one row's 13 interval-polynomials.
    if (t < PROWS) {
        const int r = ((t & 31) << 2) | (t >> 5);        // r2(r) == t
        const float* src = coeff + (panel * PROWS + r) * NB;
        float w[16];
        w[0] = w[1] = w[2] = 0.0f;
        w[13] = w[14] = w[15] = 0.0f;
        #pragma unroll
        for (int c = 0; c < 5; ++c) {
            const float2 p = reinterpret_cast<const float2*>(src)[c];
            w[3 + 2 * c] = p.x;
            w[4 + 2 * c] = p.y;
        }
        #pragma unroll
        for (int j = 0; j < NJ; ++j) {
            const float d0 = w[j], d1 = w[j + 1], d2 = w[j + 2], d3 = w[j + 3];
            float4 a;
            a.x = fmaf(4.0f, d1, d0 + d2) * (1.0f / 6.0f);      // a0
            a.y = (d2 - d0) * 0.5f;                             // a1
            a.z = (d0 + d2) * 0.5f - d1;                        // a2
            a.w = (d3 - d0) * (1.0f / 6.0f) + (d1 - d2) * 0.5f; // a3
            lds4[j * PROWS + t] = a;   // consecutive slots per lane: conflict-free
        }
    }
    __syncthreads();

    // Hoist all x loads: 4 independent float4 loads in flight.
    float4 xv[ITERS];
    int E4[ITERS];
    #pragma unroll
    for (int k = 0; k < ITERS; ++k) {
        const int row = (rg + k * 256) * 8 + wr;         // batch row
        E4[k] = row * 256 + panel * 32 + fg;             // float4 index
        xv[k] = reinterpret_cast<const float4*>(x)[E4[k]];
    }

    const float4* lbase = lds4 + fg;    // + e*32 + j*PROWS

    #pragma unroll
    for (int k = 0; k < ITERS; ++k) {
        const float xs[4] = {xv[k].x, xv[k].y, xv[k].z, xv[k].w};
        float res[4];
        #pragma unroll
        for (int e = 0; e < 4; ++e) {
            const float xc = fminf(fmaxf(xs[e], -1.0f), 1.0f);
            const float u = fmaf(xc, 6.5f, 6.5f);        // knot units [0,13]
            const float jf = fminf(truncf(u), 12.0f);
            const float tt = u - jf;                     // [0,1]
            const int j = (int)jf;

            const float4 a = lbase[e * 32 + j * PROWS];  // 1x ds_read_b128
            float r = fmaf(a.w, tt, a.z);
            r = fmaf(r, tt, a.y);
            r = fmaf(r, tt, a.x);
            // x==+1 (j=12, tt=1) / x==-1 (j=0, tt=0): zero pads give ~0
            // (<= ~1e-7), matching the reference's empty-indicator edges.
            res[e] = r;
        }
        const f32x4 ov = {res[0], res[1], res[2], res[3]};
        // Non-temporal: out is write-once, never read -> don't allocate in
        // L2/L3; keeps x L3-resident across timed replays.
        __builtin_nontemporal_store(ov, reinterpret_cast<f32x4*>(out) + E4[k]);
    }
}

extern "C" void kernel_launch(void* const* d_in, const int* in_sizes, int n_in,
                              void* d_out, int out_size, void* d_ws, size_t ws_size,
                              hipStream_t stream) {
    const float* x = (const float*)d_in[0];
    const float* coeff = (const float*)d_in[1];
    float* out = (float*)d_out;
    hipLaunchKernelGGL(bspline_act_kernel, dim3(GRID), dim3(THREADS), 0, stream,
                       x, coeff, out);
}

// Round 10
// 13.704 us; speedup vs baseline: 1.2846x; 1.0538x over previous
//
#include <hip/hip_runtime.h>

// B-spline activation (KAN-style), fp32.
// x: (8192, 1024) f32, coeff: (1024, 10) f32, out: (8192, 1024) f32.
// Structure = round-5/9: per-(feature, interval) power-basis float4 in LDS;
// tap fetch = ONE ds_read_b128 (bank pattern j-independent); 3 Horner FMAs;
// NT out stores (keep x L3-resident; r9: 15.9 -> 14.4us).
// Round-10 lever: GRID=1024 x ITERS=8 -> exactly 4 blocks/CU, ALL resident
// (one generation): staging prologue paid once, fully parallel, no block
// turnover; 8 outstanding x-loads/thread for MLP.

typedef float f32x4 __attribute__((ext_vector_type(4)));

constexpr int NB = 10;           // N_BASES
constexpr int THREADS = 256;
constexpr int GRID = 1024;
constexpr int ITERS = 8;
constexpr int PROWS = 128;       // features per panel (8 panels)
constexpr int NJ = 13;           // intervals

__global__ __launch_bounds__(THREADS) void bspline_act_kernel(
    const float* __restrict__ x,
    const float* __restrict__ coeff,
    float* __restrict__ out)
{
    // lds4[j * PROWS + s]; slot s holds logical row r(s) = ((s&31)<<2)|(s>>5),
    // so the reader of feature-group fg, element e hits slot e*32+fg.
    __shared__ float4 lds4[NJ * PROWS];          // 26 KB -> 6 blocks/CU capacity
    const int t = threadIdx.x;
    const int b = blockIdx.x;
    const int panel = b & 7;                     // 128-feature panel
    const int rg = b >> 3;                       // 0..127
    const int fg = t & 31;                       // feature group (4 features)
    const int wr = t >> 5;                       // 0..7: batch row within stripe

    // Staging: threads 0..127 each build one row's 13 interval-polynomials.
    if (t < PROWS) {
        const int r = ((t & 31) << 2) | (t >> 5);        // r2(r) == t
        const float* src = coeff + (panel * PROWS + r) * NB;
        float w[16];
        w[0] = w[1] = w[2] = 0.0f;
        w[13] = w[14] = w[15] = 0.0f;
        #pragma unroll
        for (int c = 0; c < 5; ++c) {
            const float2 p = reinterpret_cast<const float2*>(src)[c];
            w[3 + 2 * c] = p.x;
            w[4 + 2 * c] = p.y;
        }
        #pragma unroll
        for (int j = 0; j < NJ; ++j) {
            const float d0 = w[j], d1 = w[j + 1], d2 = w[j + 2], d3 = w[j + 3];
            float4 a;
            a.x = fmaf(4.0f, d1, d0 + d2) * (1.0f / 6.0f);      // a0
            a.y = (d2 - d0) * 0.5f;                             // a1
            a.z = (d0 + d2) * 0.5f - d1;                        // a2
            a.w = (d3 - d0) * (1.0f / 6.0f) + (d1 - d2) * 0.5f; // a3
            lds4[j * PROWS + t] = a;   // consecutive slots per lane: conflict-free
        }
    }
    __syncthreads();

    // Hoist all x loads: 8 independent float4 loads in flight.
    float4 xv[ITERS];
    int E4[ITERS];
    #pragma unroll
    for (int k = 0; k < ITERS; ++k) {
        const int row = (rg + k * 128) * 8 + wr;         // batch row
        E4[k] = row * 256 + panel * 32 + fg;             // float4 index
        xv[k] = reinterpret_cast<const float4*>(x)[E4[k]];
    }

    const float4* lbase = lds4 + fg;    // + e*32 + j*PROWS

    #pragma unroll
    for (int k = 0; k < ITERS; ++k) {
        const float xs[4] = {xv[k].x, xv[k].y, xv[k].z, xv[k].w};
        float res[4];
        #pragma unroll
        for (int e = 0; e < 4; ++e) {
            const float xc = fminf(fmaxf(xs[e], -1.0f), 1.0f);
            const float u = fmaf(xc, 6.5f, 6.5f);        // knot units [0,13]
            const float jf = fminf(truncf(u), 12.0f);
            const float tt = u - jf;                     // [0,1]
            const int j = (int)jf;

            const float4 a = lbase[e * 32 + j * PROWS];  // 1x ds_read_b128
            float r = fmaf(a.w, tt, a.z);
            r = fmaf(r, tt, a.y);
            r = fmaf(r, tt, a.x);
            // x==+1 (j=12, tt=1) / x==-1 (j=0, tt=0): zero pads give ~0
            // (<= ~1e-7), matching the reference's empty-indicator edges.
            res[e] = r;
        }
        const f32x4 ov = {res[0], res[1], res[2], res[3]};
        // NT: out is write-once, never read -> don't allocate in L2/L3.
        __builtin_nontemporal_store(ov, reinterpret_cast<f32x4*>(out) + E4[k]);
    }
}

extern "C" void kernel_launch(void* const* d_in, const int* in_sizes, int n_in,
                              void* d_out, int out_size, void* d_ws, size_t ws_size,
                              hipStream_t stream) {
    const float* x = (const float*)d_in[0];
    const float* coeff = (const float*)d_in[1];
    float* out = (float*)d_out;
    hipLaunchKernelGGL(bspline_act_kernel, dim3(GRID), dim3(THREADS), 0, stream,
                       x, coeff, out);
}